// Round 1
// baseline (497.515 us; speedup 1.0000x reference)
//
#include <hip/hip_runtime.h>

// ---------------------------------------------------------------------------
// FlashAttentionV2: out = Attn(x) with
//   q = x@Wq^T, k = x@Wk^T, v = x@Wv^T  (per-head dh=64, H=16)
//   scores = causal(q k^T / 8), softmax, attn@V, then @Wo^T
// B=2, T=2048, D=1024, H=16, dh=64.
// Strategy: cast to bf16, MFMA GEMMs (16x16x32), fused flash attention.
// ---------------------------------------------------------------------------

typedef __attribute__((ext_vector_type(8))) short bf16x8;
typedef __attribute__((ext_vector_type(4))) short short4v;
typedef __attribute__((ext_vector_type(4))) float f32x4;

#define T_SEQ 2048
#define D_MODEL 1024
#define NHEAD 16
#define DHEAD 64

__device__ inline short f2bf(float f) {
    unsigned u = __float_as_uint(f);
    u += 0x7fffu + ((u >> 16) & 1u);   // round-to-nearest-even
    return (short)(u >> 16);
}

__device__ inline f32x4 mfma16(bf16x8 a, bf16x8 b, f32x4 c) {
    return __builtin_amdgcn_mfma_f32_16x16x32_bf16(a, b, c, 0, 0, 0);
}

// ---------------------------------------------------------------------------
// fp32 -> bf16 cast, 4 elems/thread
// ---------------------------------------------------------------------------
__global__ __launch_bounds__(256) void cast_kernel(const float* __restrict__ s,
                                                   short* __restrict__ d, int n) {
    int i = (blockIdx.x * 256 + threadIdx.x) * 4;
    if (i >= n) return;
    float4 v = *(const float4*)(s + i);
    short4v o = { f2bf(v.x), f2bf(v.y), f2bf(v.z), f2bf(v.w) };
    *(short4v*)(d + i) = o;
}

// ---------------------------------------------------------------------------
// C[M,N] = A[M,K] * B[N,K]^T   (bf16 in, fp32 accum)
// Block: 256 thr = 4 waves, tile 128x64 (wave tile 32x64). K multiple of 32.
// MODE 0: store bf16 into (B,H,T,dh) layout (row=(b,t), col=(h,d))   [Q,K]
// MODE 1: store bf16 into (B,H,dh,T) layout (row=(h,d), col=(b,t))   [V^T]
// MODE 2: store fp32 row-major M x N                                  [out]
// A-frag: m=lane&15, k=8*(lane>>4)+i ; B-frag: n=lane&15, k=8*(lane>>4)+i
// D: col(n)=lane&15, row(m)=(lane>>4)*4+reg   (guide-verified layouts)
// ---------------------------------------------------------------------------
template <int MODE>
__global__ __launch_bounds__(256) void gemm_bt(const short* __restrict__ A,
                                               const short* __restrict__ B,
                                               void* __restrict__ C,
                                               int M, int N, int K) {
    const int wave = threadIdx.x >> 6;
    const int lane = threadIdx.x & 63;
    const int g = lane >> 4, ln = lane & 15;
    const int m_base = blockIdx.x * 128 + wave * 32;
    const int n_base = blockIdx.y * 64;

    const short* Ap0 = A + (long)(m_base + ln) * K + 8 * g;
    const short* Ap1 = Ap0 + 16 * (long)K;
    const short* Bp[4];
#pragma unroll
    for (int nf = 0; nf < 4; nf++)
        Bp[nf] = B + (long)(n_base + nf * 16 + ln) * K + 8 * g;

    f32x4 acc[2][4];
#pragma unroll
    for (int i = 0; i < 2; i++)
#pragma unroll
        for (int j = 0; j < 4; j++) acc[i][j] = (f32x4){0.f, 0.f, 0.f, 0.f};

    for (int k = 0; k < K; k += 32) {
        bf16x8 a0 = *(const bf16x8*)(Ap0 + k);
        bf16x8 a1 = *(const bf16x8*)(Ap1 + k);
#pragma unroll
        for (int nf = 0; nf < 4; nf++) {
            bf16x8 b = *(const bf16x8*)(Bp[nf] + k);
            acc[0][nf] = mfma16(a0, b, acc[0][nf]);
            acc[1][nf] = mfma16(a1, b, acc[1][nf]);
        }
    }

#pragma unroll
    for (int ms = 0; ms < 2; ms++) {
#pragma unroll
        for (int nf = 0; nf < 4; nf++) {
#pragma unroll
            for (int r = 0; r < 4; r++) {
                int row = m_base + ms * 16 + g * 4 + r;
                int col = n_base + nf * 16 + ln;
                float v = acc[ms][nf][r];
                if (MODE == 2) {
                    ((float*)C)[(long)row * N + col] = v;
                } else if (MODE == 0) {
                    // row=(b,t), col=(h,d) -> [((b*H+h)*T + t)*dh + d]
                    int b = row >> 11, t = row & 2047;
                    int h = col >> 6, d = col & 63;
                    ((short*)C)[(((long)(b * NHEAD + h) * T_SEQ + t) << 6) + d] = f2bf(v);
                } else {
                    // MODE 1: row=(h*64+d) in [0,1024), col=(b,t)
                    // -> [((b*H+h)*dh + d)*T + t] = [(b*1024 + row)*T + t]
                    int b = col >> 11, t = col & 2047;
                    ((short*)C)[((long)(b * 1024 + row) << 11) + t] = f2bf(v);
                }
            }
        }
    }
}

// ---------------------------------------------------------------------------
// Flash attention (causal), bf16 MFMA.
// Grid: (T/64, B*H). Block: 256 thr = 4 waves; wave handles 16 Q rows.
// Q,K in (B,H,T,64); Vt in (B,H,64,T). Output bf16 (B,T,H*dh) row-major.
// Online softmax in log2 domain (scale*log2e folded into sc).
// ---------------------------------------------------------------------------
__global__ __launch_bounds__(256) void flash_attn(const short* __restrict__ Q,
                                                  const short* __restrict__ Kx,
                                                  const short* __restrict__ Vt,
                                                  short* __restrict__ O) {
    __shared__ short ldsP[4][16][40];  // per-wave 16x32 P tile, padded stride 40

    const int wave = threadIdx.x >> 6;
    const int lane = threadIdx.x & 63;
    const int g = lane >> 4, ln = lane & 15;
    const int qb = blockIdx.x;   // 0..31
    const int bh = blockIdx.y;   // b*16+h
    const int qrow0 = qb * 64 + wave * 16;

    const short* Qp = Q + ((long)bh * T_SEQ + qrow0) * DHEAD;
    const short* Kp = Kx + (long)bh * T_SEQ * DHEAD;
    const short* Vp = Vt + (long)bh * DHEAD * T_SEQ;

    bf16x8 qf0 = *(const bf16x8*)(Qp + ln * 64 + 8 * g);
    bf16x8 qf1 = *(const bf16x8*)(Qp + ln * 64 + 32 + 8 * g);

    f32x4 o[4];
#pragma unroll
    for (int nf = 0; nf < 4; nf++) o[nf] = (f32x4){0.f, 0.f, 0.f, 0.f};
    float mi[4], li[4];
#pragma unroll
    for (int r = 0; r < 4; r++) { mi[r] = -INFINITY; li[r] = 0.f; }

    const float sc = 0.125f * 1.44269504089f;  // 1/sqrt(dh) * log2(e)
    const int ktmax = (qrow0 + 15) >> 5;

    for (int kt = 0; kt <= ktmax; kt++) {
        const int j0 = kt * 32;
        const short* kr = Kp + (j0 + ln) * 64 + 8 * g;
        bf16x8 kf00 = *(const bf16x8*)(kr);
        bf16x8 kf01 = *(const bf16x8*)(kr + 32);
        bf16x8 kf10 = *(const bf16x8*)(kr + 16 * 64);
        bf16x8 kf11 = *(const bf16x8*)(kr + 16 * 64 + 32);

        f32x4 s0 = (f32x4){0.f, 0.f, 0.f, 0.f};
        f32x4 s1 = (f32x4){0.f, 0.f, 0.f, 0.f};
        s0 = mfma16(qf0, kf00, s0);
        s0 = mfma16(qf1, kf01, s0);
        s1 = mfma16(qf0, kf10, s1);
        s1 = mfma16(qf1, kf11, s1);

        float v0[4], v1[4], mn[4], al[4];
#pragma unroll
        for (int r = 0; r < 4; r++) {
            int rr = qrow0 + g * 4 + r;
            v0[r] = (j0 + ln <= rr) ? s0[r] * sc : -INFINITY;
            v1[r] = (j0 + 16 + ln <= rr) ? s1[r] * sc : -INFINITY;
            float tm = fmaxf(v0[r], v1[r]);
            tm = fmaxf(tm, __shfl_xor(tm, 1));
            tm = fmaxf(tm, __shfl_xor(tm, 2));
            tm = fmaxf(tm, __shfl_xor(tm, 4));
            tm = fmaxf(tm, __shfl_xor(tm, 8));
            mn[r] = fmaxf(mi[r], tm);
            al[r] = exp2f(mi[r] - mn[r]);
            mi[r] = mn[r];
        }
#pragma unroll
        for (int r = 0; r < 4; r++) {
            float e0 = exp2f(v0[r] - mn[r]);
            float e1 = exp2f(v1[r] - mn[r]);
            float rs = e0 + e1;
            rs += __shfl_xor(rs, 1);
            rs += __shfl_xor(rs, 2);
            rs += __shfl_xor(rs, 4);
            rs += __shfl_xor(rs, 8);
            li[r] = li[r] * al[r] + rs;
            ldsP[wave][g * 4 + r][ln] = f2bf(e0);
            ldsP[wave][g * 4 + r][16 + ln] = f2bf(e1);
        }
#pragma unroll
        for (int nf = 0; nf < 4; nf++)
#pragma unroll
            for (int r = 0; r < 4; r++) o[nf][r] *= al[r];

        // P: C-layout -> A-layout via LDS (in-wave; explicit drain, no barrier)
        asm volatile("s_waitcnt lgkmcnt(0)" ::: "memory");
        bf16x8 pa = *(const bf16x8*)(&ldsP[wave][ln][8 * g]);

#pragma unroll
        for (int nf = 0; nf < 4; nf++) {
            bf16x8 vf = *(const bf16x8*)(Vp + (nf * 16 + ln) * T_SEQ + j0 + 8 * g);
            o[nf] = mfma16(pa, vf, o[nf]);
        }
    }

    const int b = bh >> 4, h = bh & 15;
#pragma unroll
    for (int nf = 0; nf < 4; nf++) {
#pragma unroll
        for (int r = 0; r < 4; r++) {
            int rr = qrow0 + g * 4 + r;
            float v = o[nf][r] / (li[r] + 1e-9f);
            O[((long)(b * T_SEQ + rr) << 10) + h * 64 + nf * 16 + ln] = f2bf(v);
        }
    }
}

// ---------------------------------------------------------------------------
extern "C" void kernel_launch(void* const* d_in, const int* in_sizes, int n_in,
                              void* d_out, int out_size, void* d_ws, size_t ws_size,
                              hipStream_t stream) {
    const float* x  = (const float*)d_in[0];
    const float* Wq = (const float*)d_in[1];
    const float* Wk = (const float*)d_in[2];
    const float* Wv = (const float*)d_in[3];
    const float* Wo = (const float*)d_in[4];

    char* ws = (char*)d_ws;
    short* xb  = (short*)(ws + (0ull  << 20));  // 8 MB  (2*2048*1024 bf16)
    short* wqb = (short*)(ws + (8ull  << 20));  // 2 MB
    short* wkb = (short*)(ws + (10ull << 20));
    short* wvb = (short*)(ws + (12ull << 20));
    short* wob = (short*)(ws + (14ull << 20));
    short* Qb  = (short*)(ws + (16ull << 20));  // 8 MB (B,H,T,64)
    short* Kb  = (short*)(ws + (24ull << 20));  // 8 MB (B,H,T,64)
    short* Vtb = (short*)(ws + (32ull << 20));  // 8 MB (B,H,64,T)
    short* Ab  = (short*)(ws + (40ull << 20));  // 8 MB (B,T,1024)

    cast_kernel<<<4096, 256, 0, stream>>>(x, xb, 2 * T_SEQ * D_MODEL);
    cast_kernel<<<1024, 256, 0, stream>>>(Wq, wqb, D_MODEL * D_MODEL);
    cast_kernel<<<1024, 256, 0, stream>>>(Wk, wkb, D_MODEL * D_MODEL);
    cast_kernel<<<1024, 256, 0, stream>>>(Wv, wvb, D_MODEL * D_MODEL);
    cast_kernel<<<1024, 256, 0, stream>>>(Wo, wob, D_MODEL * D_MODEL);

    dim3 gqk(4096 / 128, 1024 / 64);  // M=4096 (b,t), N=1024 (h,d)
    gemm_bt<0><<<gqk, 256, 0, stream>>>(xb, wqb, Qb, 4096, 1024, 1024);
    gemm_bt<0><<<gqk, 256, 0, stream>>>(xb, wkb, Kb, 4096, 1024, 1024);

    dim3 gvt(1024 / 128, 4096 / 64);  // C^T: M=1024 (h,d), N=4096 (b,t)
    gemm_bt<1><<<gvt, 256, 0, stream>>>(wvb, xb, Vtb, 1024, 4096, 1024);

    dim3 gat(T_SEQ / 64, 2 * NHEAD);
    flash_attn<<<gat, 256, 0, stream>>>(Qb, Kb, Vtb, Ab);

    gemm_bt<2><<<gqk, 256, 0, stream>>>(Ab, wob, d_out, 4096, 1024, 1024);
}

// Round 2
// 391.609 us; speedup vs baseline: 1.2704x; 1.2704x over previous
//
#include <hip/hip_runtime.h>

// ---------------------------------------------------------------------------
// FlashAttentionV2 on MI355X. bf16 MFMA (16x16x32) throughout.
// R1 changes: m97-style LDS-staged GEMM (global_load_lds w=16, 128x64 tile),
// flash_attn with 64-key tiles, uniform per-block trip count, LPT dispatch,
// K-prefetch + early V loads.
// ---------------------------------------------------------------------------

typedef __attribute__((ext_vector_type(8))) short bf16x8;
typedef __attribute__((ext_vector_type(4))) short short4v;
typedef __attribute__((ext_vector_type(4))) float f32x4;

#define T_SEQ 2048
#define D_MODEL 1024
#define NHEAD 16
#define DHEAD 64

__device__ inline short f2bf(float f) {
    unsigned u = __float_as_uint(f);
    u += 0x7fffu + ((u >> 16) & 1u);   // RNE
    return (short)(u >> 16);
}

__device__ inline f32x4 mfma16(bf16x8 a, bf16x8 b, f32x4 c) {
    return __builtin_amdgcn_mfma_f32_16x16x32_bf16(a, b, c, 0, 0, 0);
}

__device__ inline void gld_lds16(const short* g, short* l) {
    __builtin_amdgcn_global_load_lds(
        (const __attribute__((address_space(1))) void*)g,
        (__attribute__((address_space(3))) void*)l, 16, 0, 0);
}

// ---------------------------------------------------------------------------
__global__ __launch_bounds__(256) void cast_kernel(const float* __restrict__ s,
                                                   short* __restrict__ d, int n) {
    int i = (blockIdx.x * 256 + threadIdx.x) * 4;
    if (i >= n) return;
    float4 v = *(const float4*)(s + i);
    short4v o = { f2bf(v.x), f2bf(v.y), f2bf(v.z), f2bf(v.w) };
    *(short4v*)(d + i) = o;
}

// ---------------------------------------------------------------------------
// C[M,N] = A[M,K] * B[N,K]^T, bf16 in fp32 accum. Block tile 128x64, BK=32.
// 256 thr = 4 waves in 2x2; wave tile 64x32 (4 m-frags x 2 n-frags).
// LDS staged via global_load_lds width=16 (wave-uniform-base + lane*16).
// MODE 0: bf16 -> (B,H,T,dh) [Q,K] | MODE 1: bf16 -> (B,H,dh,T) [V^T]
// MODE 2: fp32 row-major [final out]
// ---------------------------------------------------------------------------
template <int MODE>
__global__ __launch_bounds__(256, 2) void gemm_bt(const short* __restrict__ A,
                                                  const short* __restrict__ B,
                                                  void* __restrict__ C,
                                                  int M, int N, int K) {
    __shared__ short As[128 * 32];   // 8 KB, row-major rows x 32k
    __shared__ short Bs[64 * 32];    // 4 KB

    const int tid = threadIdx.x;
    const int wave = tid >> 6, lane = tid & 63;
    const int g = lane >> 4, ln = lane & 15;
    const int mh = wave & 1, nh = wave >> 1;
    const int m_base = blockIdx.x * 128;
    const int n_base = blockIdx.y * 64;

    // staging: thread t covers LDS bytes [t*16, t*16+16) (+4096 for A shot 1)
    const int srow = tid >> 2;              // (t*16)/64
    const int sinner = (tid & 3) * 8;       // shorts within row
    const short* Ag0 = A + (long)(m_base + srow) * K + sinner;
    const short* Ag1 = Ag0 + 64 * (long)K;
    const short* Bg  = B + (long)(n_base + srow) * K + sinner;

    f32x4 acc[4][2];
#pragma unroll
    for (int i = 0; i < 4; i++)
#pragma unroll
        for (int j = 0; j < 2; j++) acc[i][j] = (f32x4){0.f, 0.f, 0.f, 0.f};

    for (int k0 = 0; k0 < K; k0 += 32) {
        gld_lds16(Ag0 + k0, As + tid * 8);
        gld_lds16(Ag1 + k0, As + 2048 + tid * 8);
        gld_lds16(Bg + k0, Bs + tid * 8);
        __syncthreads();   // vmcnt(0) drain + barrier: staged data visible

        bf16x8 a[4], b[2];
#pragma unroll
        for (int mf = 0; mf < 4; mf++)
            a[mf] = *(const bf16x8*)(As + (mh * 64 + mf * 16 + ln) * 32 + g * 8);
#pragma unroll
        for (int nf = 0; nf < 2; nf++)
            b[nf] = *(const bf16x8*)(Bs + (nh * 32 + nf * 16 + ln) * 32 + g * 8);
#pragma unroll
        for (int mf = 0; mf < 4; mf++)
#pragma unroll
            for (int nf = 0; nf < 2; nf++)
                acc[mf][nf] = mfma16(a[mf], b[nf], acc[mf][nf]);
        __syncthreads();   // readers done before next stage overwrites
    }

#pragma unroll
    for (int mf = 0; mf < 4; mf++) {
#pragma unroll
        for (int nf = 0; nf < 2; nf++) {
#pragma unroll
            for (int r = 0; r < 4; r++) {
                int row = m_base + mh * 64 + mf * 16 + g * 4 + r;
                int col = n_base + nh * 32 + nf * 16 + ln;
                float v = acc[mf][nf][r];
                if (MODE == 2) {
                    ((float*)C)[(long)row * N + col] = v;
                } else if (MODE == 0) {
                    int b_ = row >> 11, t = row & 2047;
                    int h = col >> 6, d = col & 63;
                    ((short*)C)[(((long)(b_ * NHEAD + h) * T_SEQ + t) << 6) + d] = f2bf(v);
                } else {
                    int b_ = col >> 11, t = col & 2047;
                    ((short*)C)[((long)(b_ * 1024 + row) << 11) + t] = f2bf(v);
                }
            }
        }
    }
}

// ---------------------------------------------------------------------------
// Flash attention (causal). Grid (32, B*H), block 4 waves x 16 Q rows.
// 64-key tiles; diagonal tile masked; uniform trip count qb+1 for all waves.
// LPT: qb = 31 - blockIdx.x so longest blocks dispatch first.
// ---------------------------------------------------------------------------
__global__ __launch_bounds__(256) void flash_attn(const short* __restrict__ Q,
                                                  const short* __restrict__ Kx,
                                                  const short* __restrict__ Vt,
                                                  short* __restrict__ O) {
    __shared__ short ldsP[4][16][72];   // per-wave 16x64 P tile, stride 72

    const int wave = threadIdx.x >> 6;
    const int lane = threadIdx.x & 63;
    const int g = lane >> 4, ln = lane & 15;
    const int qb = 31 - blockIdx.x;     // LPT schedule
    const int bh = blockIdx.y;
    const int qrow0 = qb * 64 + wave * 16;

    const short* Qp = Q + ((long)bh * T_SEQ + qrow0) * DHEAD;
    const short* Kp = Kx + (long)bh * T_SEQ * DHEAD;
    const short* Vp = Vt + (long)bh * DHEAD * T_SEQ;

    bf16x8 qf0 = *(const bf16x8*)(Qp + ln * 64 + 8 * g);
    bf16x8 qf1 = *(const bf16x8*)(Qp + ln * 64 + 32 + 8 * g);

    f32x4 o[4];
#pragma unroll
    for (int nf = 0; nf < 4; nf++) o[nf] = (f32x4){0.f, 0.f, 0.f, 0.f};
    float mi[4], li[4];
#pragma unroll
    for (int r = 0; r < 4; r++) { mi[r] = -INFINITY; li[r] = 0.f; }

    const float sc = 0.125f * 1.44269504089f;  // 1/sqrt(dh) * log2(e)
    const int ntiles = qb + 1;

    const short* Kbase = Kp + ln * 64 + 8 * g;  // + i*4096 + j*1024 + c*32
    const short* Vb[4];
#pragma unroll
    for (int nf = 0; nf < 4; nf++) Vb[nf] = Vp + (nf * 16 + ln) * T_SEQ + 8 * g;

    bf16x8 kf[4][2];
#pragma unroll
    for (int j = 0; j < 4; j++)
#pragma unroll
        for (int c = 0; c < 2; c++)
            kf[j][c] = *(const bf16x8*)(Kbase + j * 1024 + c * 32);

    for (int i = 0; i < ntiles; i++) {
        const int j0 = i * 64;

        f32x4 s[4];
#pragma unroll
        for (int j = 0; j < 4; j++) {
            s[j] = mfma16(qf0, kf[j][0], (f32x4){0.f, 0.f, 0.f, 0.f});
            s[j] = mfma16(qf1, kf[j][1], s[j]);
        }

        // V loads for this tile (overlap with softmax VALU)
        bf16x8 vf[4][2];
#pragma unroll
        for (int nf = 0; nf < 4; nf++)
#pragma unroll
            for (int c = 0; c < 2; c++)
                vf[nf][c] = *(const bf16x8*)(Vb[nf] + j0 + 32 * c);

        // prefetch next K tile
        if (i + 1 < ntiles) {
            const short* kn = Kbase + (long)(i + 1) * 4096;
#pragma unroll
            for (int j = 0; j < 4; j++)
#pragma unroll
                for (int c = 0; c < 2; c++)
                    kf[j][c] = *(const bf16x8*)(kn + j * 1024 + c * 32);
        }

        if (i == ntiles - 1) {
            // diagonal tile: mask keys > row. key-local = 16j+ln, row-local
            // = 16*wave + g*4 + r (independent of qb).
            const int rl = 16 * wave + g * 4;
#pragma unroll
            for (int j = 0; j < 4; j++) {
                int kl = 16 * j + ln;
#pragma unroll
                for (int r = 0; r < 4; r++)
                    if (kl > rl + r) s[j][r] = -INFINITY;
            }
        }

        float al[4];
#pragma unroll
        for (int r = 0; r < 4; r++) {
            float tm = fmaxf(fmaxf(s[0][r], s[1][r]), fmaxf(s[2][r], s[3][r]));
            tm = fmaxf(tm, __shfl_xor(tm, 1));
            tm = fmaxf(tm, __shfl_xor(tm, 2));
            tm = fmaxf(tm, __shfl_xor(tm, 4));
            tm = fmaxf(tm, __shfl_xor(tm, 8));
            float mn = fmaxf(mi[r], tm * sc);
            al[r] = exp2f(mi[r] - mn);
            mi[r] = mn;
            float e0 = exp2f(fmaf(s[0][r], sc, -mn));
            float e1 = exp2f(fmaf(s[1][r], sc, -mn));
            float e2 = exp2f(fmaf(s[2][r], sc, -mn));
            float e3 = exp2f(fmaf(s[3][r], sc, -mn));
            float rs = (e0 + e1) + (e2 + e3);
            rs += __shfl_xor(rs, 1);
            rs += __shfl_xor(rs, 2);
            rs += __shfl_xor(rs, 4);
            rs += __shfl_xor(rs, 8);
            li[r] = fmaf(li[r], al[r], rs);
            ldsP[wave][g * 4 + r][ln] = f2bf(e0);
            ldsP[wave][g * 4 + r][16 + ln] = f2bf(e1);
            ldsP[wave][g * 4 + r][32 + ln] = f2bf(e2);
            ldsP[wave][g * 4 + r][48 + ln] = f2bf(e3);
        }
#pragma unroll
        for (int nf = 0; nf < 4; nf++)
#pragma unroll
            for (int r = 0; r < 4; r++) o[nf][r] *= al[r];

        // P: C-layout -> A-layout via per-wave LDS (in-wave drain only)
        asm volatile("s_waitcnt lgkmcnt(0)" ::: "memory");
        bf16x8 pa0 = *(const bf16x8*)(&ldsP[wave][ln][8 * g]);
        bf16x8 pa1 = *(const bf16x8*)(&ldsP[wave][ln][32 + 8 * g]);

#pragma unroll
        for (int nf = 0; nf < 4; nf++) {
            o[nf] = mfma16(pa0, vf[nf][0], o[nf]);
            o[nf] = mfma16(pa1, vf[nf][1], o[nf]);
        }
    }

    const int b = bh >> 4, h = bh & 15;
#pragma unroll
    for (int nf = 0; nf < 4; nf++) {
#pragma unroll
        for (int r = 0; r < 4; r++) {
            int rr = qrow0 + g * 4 + r;
            float v = o[nf][r] / (li[r] + 1e-9f);
            O[((long)(b * T_SEQ + rr) << 10) + h * 64 + nf * 16 + ln] = f2bf(v);
        }
    }
}

// ---------------------------------------------------------------------------
extern "C" void kernel_launch(void* const* d_in, const int* in_sizes, int n_in,
                              void* d_out, int out_size, void* d_ws, size_t ws_size,
                              hipStream_t stream) {
    const float* x  = (const float*)d_in[0];
    const float* Wq = (const float*)d_in[1];
    const float* Wk = (const float*)d_in[2];
    const float* Wv = (const float*)d_in[3];
    const float* Wo = (const float*)d_in[4];

    char* ws = (char*)d_ws;
    short* xb  = (short*)(ws + (0ull  << 20));
    short* wqb = (short*)(ws + (8ull  << 20));
    short* wkb = (short*)(ws + (10ull << 20));
    short* wvb = (short*)(ws + (12ull << 20));
    short* wob = (short*)(ws + (14ull << 20));
    short* Qb  = (short*)(ws + (16ull << 20));  // (B,H,T,64)
    short* Kb  = (short*)(ws + (24ull << 20));  // (B,H,T,64)
    short* Vtb = (short*)(ws + (32ull << 20));  // (B,H,64,T)
    short* Ab  = (short*)(ws + (40ull << 20));  // (B,T,1024)

    cast_kernel<<<4096, 256, 0, stream>>>(x, xb, 2 * T_SEQ * D_MODEL);
    cast_kernel<<<1024, 256, 0, stream>>>(Wq, wqb, D_MODEL * D_MODEL);
    cast_kernel<<<1024, 256, 0, stream>>>(Wk, wkb, D_MODEL * D_MODEL);
    cast_kernel<<<1024, 256, 0, stream>>>(Wv, wvb, D_MODEL * D_MODEL);
    cast_kernel<<<1024, 256, 0, stream>>>(Wo, wob, D_MODEL * D_MODEL);

    dim3 gqk(4096 / 128, 1024 / 64);
    gemm_bt<0><<<gqk, 256, 0, stream>>>(xb, wqb, Qb, 4096, 1024, 1024);
    gemm_bt<0><<<gqk, 256, 0, stream>>>(xb, wkb, Kb, 4096, 1024, 1024);

    dim3 gvt(1024 / 128, 4096 / 64);
    gemm_bt<1><<<gvt, 256, 0, stream>>>(wvb, xb, Vtb, 1024, 4096, 1024);

    dim3 gat(T_SEQ / 64, 2 * NHEAD);
    flash_attn<<<gat, 256, 0, stream>>>(Qb, Kb, Vtb, Ab);

    gemm_bt<2><<<gqk, 256, 0, stream>>>(Ab, wob, d_out, 4096, 1024, 1024);
}

// Round 3
// 298.664 us; speedup vs baseline: 1.6658x; 1.3112x over previous
//
#include <hip/hip_runtime.h>

// ---------------------------------------------------------------------------
// FlashAttentionV2 on MI355X. bf16 MFMA (16x16x32) throughout.
// R2 changes: flash_attn rewritten with UNNORMALIZED online softmax (no max
// reduction -> zero inner-loop shuffles, no alpha rescale; safe since
// |score*log2e| <~ 30 << fp32 range), key-split across wave pairs with
// additive (o,l) merge, paired q-tiles {x, 31-x} for uniform trip counts.
// Weight casts batched into one dispatch.
// ---------------------------------------------------------------------------

typedef __attribute__((ext_vector_type(8))) short bf16x8;
typedef __attribute__((ext_vector_type(4))) short short4v;
typedef __attribute__((ext_vector_type(4))) float f32x4;

#define T_SEQ 2048
#define D_MODEL 1024
#define NHEAD 16
#define DHEAD 64

__device__ inline short f2bf(float f) {
    unsigned u = __float_as_uint(f);
    u += 0x7fffu + ((u >> 16) & 1u);   // RNE
    return (short)(u >> 16);
}

__device__ inline f32x4 mfma16(bf16x8 a, bf16x8 b, f32x4 c) {
    return __builtin_amdgcn_mfma_f32_16x16x32_bf16(a, b, c, 0, 0, 0);
}

__device__ inline void gld_lds16(const short* g, short* l) {
    __builtin_amdgcn_global_load_lds(
        (const __attribute__((address_space(1))) void*)g,
        (__attribute__((address_space(3))) void*)l, 16, 0, 0);
}

// ---------------------------------------------------------------------------
__global__ __launch_bounds__(256) void cast_kernel(const float* __restrict__ s,
                                                   short* __restrict__ d, int n) {
    int i = (blockIdx.x * 256 + threadIdx.x) * 4;
    if (i >= n) return;
    float4 v = *(const float4*)(s + i);
    short4v o = { f2bf(v.x), f2bf(v.y), f2bf(v.z), f2bf(v.w) };
    *(short4v*)(d + i) = o;
}

// 4 weight matrices (1M elems each) in one dispatch; dsts contiguous 2MB apart
__global__ __launch_bounds__(256) void cast4_kernel(const float* __restrict__ s0,
                                                    const float* __restrict__ s1,
                                                    const float* __restrict__ s2,
                                                    const float* __restrict__ s3,
                                                    short* __restrict__ d) {
    const float* s = (blockIdx.y == 0) ? s0 : (blockIdx.y == 1) ? s1
                   : (blockIdx.y == 2) ? s2 : s3;
    int i = (blockIdx.x * 256 + threadIdx.x) * 4;
    float4 v = *(const float4*)(s + i);
    short4v o = { f2bf(v.x), f2bf(v.y), f2bf(v.z), f2bf(v.w) };
    *(short4v*)(d + blockIdx.y * 1048576 + i) = o;
}

// ---------------------------------------------------------------------------
// C[M,N] = A[M,K] * B[N,K]^T, bf16 in fp32 accum. Block tile 128x64, BK=32.
// LDS staged via global_load_lds width=16. (unchanged from R1)
// ---------------------------------------------------------------------------
template <int MODE>
__global__ __launch_bounds__(256, 2) void gemm_bt(const short* __restrict__ A,
                                                  const short* __restrict__ B,
                                                  void* __restrict__ C,
                                                  int M, int N, int K) {
    __shared__ short As[128 * 32];
    __shared__ short Bs[64 * 32];

    const int tid = threadIdx.x;
    const int wave = tid >> 6, lane = tid & 63;
    const int g = lane >> 4, ln = lane & 15;
    const int mh = wave & 1, nh = wave >> 1;
    const int m_base = blockIdx.x * 128;
    const int n_base = blockIdx.y * 64;

    const int srow = tid >> 2;
    const int sinner = (tid & 3) * 8;
    const short* Ag0 = A + (long)(m_base + srow) * K + sinner;
    const short* Ag1 = Ag0 + 64 * (long)K;
    const short* Bg  = B + (long)(n_base + srow) * K + sinner;

    f32x4 acc[4][2];
#pragma unroll
    for (int i = 0; i < 4; i++)
#pragma unroll
        for (int j = 0; j < 2; j++) acc[i][j] = (f32x4){0.f, 0.f, 0.f, 0.f};

    for (int k0 = 0; k0 < K; k0 += 32) {
        gld_lds16(Ag0 + k0, As + tid * 8);
        gld_lds16(Ag1 + k0, As + 2048 + tid * 8);
        gld_lds16(Bg + k0, Bs + tid * 8);
        __syncthreads();

        bf16x8 a[4], b[2];
#pragma unroll
        for (int mf = 0; mf < 4; mf++)
            a[mf] = *(const bf16x8*)(As + (mh * 64 + mf * 16 + ln) * 32 + g * 8);
#pragma unroll
        for (int nf = 0; nf < 2; nf++)
            b[nf] = *(const bf16x8*)(Bs + (nh * 32 + nf * 16 + ln) * 32 + g * 8);
#pragma unroll
        for (int mf = 0; mf < 4; mf++)
#pragma unroll
            for (int nf = 0; nf < 2; nf++)
                acc[mf][nf] = mfma16(a[mf], b[nf], acc[mf][nf]);
        __syncthreads();
    }

#pragma unroll
    for (int mf = 0; mf < 4; mf++) {
#pragma unroll
        for (int nf = 0; nf < 2; nf++) {
#pragma unroll
            for (int r = 0; r < 4; r++) {
                int row = m_base + mh * 64 + mf * 16 + g * 4 + r;
                int col = n_base + nh * 32 + nf * 16 + ln;
                float v = acc[mf][nf][r];
                if (MODE == 2) {
                    ((float*)C)[(long)row * N + col] = v;
                } else if (MODE == 0) {
                    int b_ = row >> 11, t = row & 2047;
                    int h = col >> 6, d = col & 63;
                    ((short*)C)[(((long)(b_ * NHEAD + h) * T_SEQ + t) << 6) + d] = f2bf(v);
                } else {
                    int b_ = col >> 11, t = col & 2047;
                    ((short*)C)[((long)(b_ * 1024 + row) << 11) + t] = f2bf(v);
                }
            }
        }
    }
}

// ---------------------------------------------------------------------------
// Flash attention (causal), unnormalized softmax (no max, no rescale).
// Grid (16, B*H), block 512 = 8 waves. Block processes q-tiles x and 31-x
// sequentially (uniform work). Waves 0-3: even key tiles; 4-7: odd key
// tiles of the same rows; partial (o, li) merged additively via LDS.
// ---------------------------------------------------------------------------
__global__ __launch_bounds__(512, 4) void flash_attn(const short* __restrict__ Q,
                                                     const short* __restrict__ Kx,
                                                     const short* __restrict__ Vt,
                                                     short* __restrict__ O) {
    __shared__ short ldsP[8][16][72];    // per-wave 16x64 P tile
    __shared__ float cmb[4][64][24];     // combine: 16 o + 4 li per lane

    const int wv = threadIdx.x >> 6;
    const int lane = threadIdx.x & 63;
    const int g = lane >> 4, ln = lane & 15;
    const int half = wv >> 2;            // key-parity this wave owns
    const int w4 = wv & 3;               // 16-row group within q-tile
    const int bh = blockIdx.y;

    const short* Kbase = Kx + (long)bh * T_SEQ * DHEAD + ln * 64 + 8 * g;
    const short* Vp = Vt + (long)bh * DHEAD * T_SEQ;
    const short* Vb[4];
#pragma unroll
    for (int nf = 0; nf < 4; nf++) Vb[nf] = Vp + (nf * 16 + ln) * T_SEQ + 8 * g;

    const float sc = 0.125f * 1.44269504089f;  // 1/sqrt(dh) * log2(e)

    for (int rep = 0; rep < 2; rep++) {
        const int qt = rep ? 31 - (int)blockIdx.x : (int)blockIdx.x;
        const int nt = qt + 1;
        const int qrow0 = qt * 64 + w4 * 16;

        const short* Qp = Q + ((long)bh * T_SEQ + qrow0) * DHEAD;
        bf16x8 qf0 = *(const bf16x8*)(Qp + ln * 64 + 8 * g);
        bf16x8 qf1 = *(const bf16x8*)(Qp + ln * 64 + 32 + 8 * g);

        f32x4 o[4];
#pragma unroll
        for (int nf = 0; nf < 4; nf++) o[nf] = (f32x4){0.f, 0.f, 0.f, 0.f};
        float li[4] = {0.f, 0.f, 0.f, 0.f};

        bf16x8 kf[4][2];
        if (half < nt) {
            const short* k0 = Kbase + (long)half * 4096;
#pragma unroll
            for (int j = 0; j < 4; j++)
#pragma unroll
                for (int c = 0; c < 2; c++)
                    kf[j][c] = *(const bf16x8*)(k0 + j * 1024 + c * 32);
        }

        for (int i = half; i < nt; i += 2) {
            f32x4 s[4];
#pragma unroll
            for (int j = 0; j < 4; j++) {
                s[j] = mfma16(qf0, kf[j][0], (f32x4){0.f, 0.f, 0.f, 0.f});
                s[j] = mfma16(qf1, kf[j][1], s[j]);
            }

            bf16x8 vf[4][2];
#pragma unroll
            for (int nf = 0; nf < 4; nf++)
#pragma unroll
                for (int c = 0; c < 2; c++)
                    vf[nf][c] = *(const bf16x8*)(Vb[nf] + i * 64 + 32 * c);

            if (i + 2 < nt) {
                const short* kn = Kbase + (long)(i + 2) * 4096;
#pragma unroll
                for (int j = 0; j < 4; j++)
#pragma unroll
                    for (int c = 0; c < 2; c++)
                        kf[j][c] = *(const bf16x8*)(kn + j * 1024 + c * 32);
            }

            if (i == nt - 1) {   // diagonal tile: mask key_local > row_local
                const int rl = w4 * 16 + g * 4;
#pragma unroll
                for (int j = 0; j < 4; j++) {
                    int kl = 16 * j + ln;
#pragma unroll
                    for (int r = 0; r < 4; r++)
                        if (kl > rl + r) s[j][r] = -INFINITY;
                }
            }

#pragma unroll
            for (int r = 0; r < 4; r++) {
                float e0 = __builtin_amdgcn_exp2f(s[0][r] * sc);
                float e1 = __builtin_amdgcn_exp2f(s[1][r] * sc);
                float e2 = __builtin_amdgcn_exp2f(s[2][r] * sc);
                float e3 = __builtin_amdgcn_exp2f(s[3][r] * sc);
                li[r] += (e0 + e1) + (e2 + e3);
                ldsP[wv][g * 4 + r][ln] = f2bf(e0);
                ldsP[wv][g * 4 + r][16 + ln] = f2bf(e1);
                ldsP[wv][g * 4 + r][32 + ln] = f2bf(e2);
                ldsP[wv][g * 4 + r][48 + ln] = f2bf(e3);
            }

            asm volatile("s_waitcnt lgkmcnt(0)" ::: "memory");
            bf16x8 pa0 = *(const bf16x8*)(&ldsP[wv][ln][8 * g]);
            bf16x8 pa1 = *(const bf16x8*)(&ldsP[wv][ln][32 + 8 * g]);

#pragma unroll
            for (int nf = 0; nf < 4; nf++) {
                o[nf] = mfma16(pa0, vf[nf][0], o[nf]);
                o[nf] = mfma16(pa1, vf[nf][1], o[nf]);
            }
        }

        // merge odd-half partials into even-half (additive: no max state)
        if (half == 1) {
            float* cb = &cmb[w4][lane][0];
#pragma unroll
            for (int nf = 0; nf < 4; nf++) *(f32x4*)(cb + 4 * nf) = o[nf];
#pragma unroll
            for (int r = 0; r < 4; r++) cb[16 + r] = li[r];
        }
        __syncthreads();
        if (half == 0) {
            const float* cb = &cmb[w4][lane][0];
#pragma unroll
            for (int nf = 0; nf < 4; nf++) {
                f32x4 t = *(const f32x4*)(cb + 4 * nf);
#pragma unroll
                for (int r = 0; r < 4; r++) o[nf][r] += t[r];
            }
#pragma unroll
            for (int r = 0; r < 4; r++) {
                float l = li[r] + cb[16 + r];
                l += __shfl_xor(l, 1);
                l += __shfl_xor(l, 2);
                l += __shfl_xor(l, 4);
                l += __shfl_xor(l, 8);
                li[r] = l;
            }
            const int b = bh >> 4, h = bh & 15;
#pragma unroll
            for (int nf = 0; nf < 4; nf++) {
#pragma unroll
                for (int r = 0; r < 4; r++) {
                    int rr = qrow0 + g * 4 + r;
                    float v = o[nf][r] / (li[r] + 1e-9f);
                    O[((long)(b * T_SEQ + rr) << 10) + h * 64 + nf * 16 + ln] = f2bf(v);
                }
            }
        }
        __syncthreads();   // cmb reused next rep
    }
}

// ---------------------------------------------------------------------------
extern "C" void kernel_launch(void* const* d_in, const int* in_sizes, int n_in,
                              void* d_out, int out_size, void* d_ws, size_t ws_size,
                              hipStream_t stream) {
    const float* x  = (const float*)d_in[0];
    const float* Wq = (const float*)d_in[1];
    const float* Wk = (const float*)d_in[2];
    const float* Wv = (const float*)d_in[3];
    const float* Wo = (const float*)d_in[4];

    char* ws = (char*)d_ws;
    short* xb  = (short*)(ws + (0ull  << 20));
    short* wqb = (short*)(ws + (8ull  << 20));   // wq,wk,wv,wo contiguous 2MB each
    short* wkb = (short*)(ws + (10ull << 20));
    short* wvb = (short*)(ws + (12ull << 20));
    short* wob = (short*)(ws + (14ull << 20));
    short* Qb  = (short*)(ws + (16ull << 20));   // (B,H,T,64)
    short* Kb  = (short*)(ws + (24ull << 20));   // (B,H,T,64)
    short* Vtb = (short*)(ws + (32ull << 20));   // (B,H,64,T)
    short* Ab  = (short*)(ws + (40ull << 20));   // (B,T,1024)

    cast_kernel<<<4096, 256, 0, stream>>>(x, xb, 2 * T_SEQ * D_MODEL);
    cast4_kernel<<<dim3(1024, 4), 256, 0, stream>>>(Wq, Wk, Wv, Wo, wqb);

    dim3 gqk(4096 / 128, 1024 / 64);
    gemm_bt<0><<<gqk, 256, 0, stream>>>(xb, wqb, Qb, 4096, 1024, 1024);
    gemm_bt<0><<<gqk, 256, 0, stream>>>(xb, wkb, Kb, 4096, 1024, 1024);

    dim3 gvt(1024 / 128, 4096 / 64);
    gemm_bt<1><<<gvt, 256, 0, stream>>>(wvb, xb, Vtb, 1024, 4096, 1024);

    dim3 gat(16, 2 * NHEAD);
    flash_attn<<<gat, 512, 0, stream>>>(Qb, Kb, Vtb, Ab);

    gemm_bt<2><<<gqk, 256, 0, stream>>>(Ab, wob, d_out, 4096, 1024, 1024);
}

// Round 4
// 183.703 us; speedup vs baseline: 2.7083x; 1.6258x over previous
//
#include <hip/hip_runtime.h>

// ---------------------------------------------------------------------------
// FlashAttentionV2 on MI355X. bf16 MFMA (16x16x32) throughout.
// R3: flash_attn LDS-staged K/V (global_load_lds w=16, double-buffered,
// 8 waves share tiles), XCD-aware bh->L2 pinning, LPT order, unnormalized
// softmax. GEMMs upgraded to m97 128x128 shape; QKV fused into one GEMM.
// ---------------------------------------------------------------------------

typedef __attribute__((ext_vector_type(8))) short bf16x8;
typedef __attribute__((ext_vector_type(4))) short short4v;
typedef __attribute__((ext_vector_type(4))) float f32x4;

#define T_SEQ 2048
#define D_MODEL 1024
#define NHEAD 16
#define DHEAD 64

__device__ inline short f2bf(float f) {
    unsigned u = __float_as_uint(f);
    u += 0x7fffu + ((u >> 16) & 1u);   // RNE
    return (short)(u >> 16);
}

__device__ inline f32x4 mfma16(bf16x8 a, bf16x8 b, f32x4 c) {
    return __builtin_amdgcn_mfma_f32_16x16x32_bf16(a, b, c, 0, 0, 0);
}

__device__ inline void gld_lds16(const short* g, short* l) {
    __builtin_amdgcn_global_load_lds(
        (const __attribute__((address_space(1))) void*)g,
        (__attribute__((address_space(3))) void*)l, 16, 0, 0);
}

// ---------------------------------------------------------------------------
__global__ __launch_bounds__(256) void cast_kernel(const float* __restrict__ s,
                                                   short* __restrict__ d, int n) {
    int i = (blockIdx.x * 256 + threadIdx.x) * 4;
    if (i >= n) return;
    float4 v = *(const float4*)(s + i);
    short4v o = { f2bf(v.x), f2bf(v.y), f2bf(v.z), f2bf(v.w) };
    *(short4v*)(d + i) = o;
}

__global__ __launch_bounds__(256) void cast4_kernel(const float* __restrict__ s0,
                                                    const float* __restrict__ s1,
                                                    const float* __restrict__ s2,
                                                    const float* __restrict__ s3,
                                                    short* __restrict__ d) {
    const float* s = (blockIdx.y == 0) ? s0 : (blockIdx.y == 1) ? s1
                   : (blockIdx.y == 2) ? s2 : s3;
    int i = (blockIdx.x * 256 + threadIdx.x) * 4;
    float4 v = *(const float4*)(s + i);
    short4v o = { f2bf(v.x), f2bf(v.y), f2bf(v.z), f2bf(v.w) };
    *(short4v*)(d + blockIdx.y * 1048576 + i) = o;
}

// ---------------------------------------------------------------------------
// C[M,N] = A[M,K] * B[N,K]^T, m97 shape: 128x128 tile, BK=32, 4 waves 2x2,
// wave tile 64x64 (4x4 frags, 16 MFMA/kstep), global_load_lds w=16 staging.
// MODE 3: QKV epilogue (n-block selects Q/K/V^T scatter, bf16)
// MODE 2: fp32 row-major
// ---------------------------------------------------------------------------
template <int MODE>
__global__ __launch_bounds__(256, 2) void gemm128(const short* __restrict__ A,
                                                  const short* __restrict__ B,
                                                  void* __restrict__ C0,
                                                  void* __restrict__ C1,
                                                  void* __restrict__ C2,
                                                  int M, int N, int K) {
    __shared__ short As[4096];   // 128 rows x 32 k
    __shared__ short Bs[4096];

    const int tid = threadIdx.x;
    const int wave = tid >> 6, lane = tid & 63;
    const int g = lane >> 4, ln = lane & 15;
    const int mh = wave & 1, nh = wave >> 1;
    const int m_base = blockIdx.x * 128;
    const int n_base = blockIdx.y * 128;

    const int srow = tid >> 2;
    const int sinner = (tid & 3) * 8;
    const short* Ag = A + (long)(m_base + srow) * K + sinner;
    const short* Bg = B + (long)(n_base + srow) * K + sinner;
    const long r64 = 64 * (long)K;

    f32x4 acc[4][4];
#pragma unroll
    for (int i = 0; i < 4; i++)
#pragma unroll
        for (int j = 0; j < 4; j++) acc[i][j] = (f32x4){0.f, 0.f, 0.f, 0.f};

    for (int k0 = 0; k0 < K; k0 += 32) {
        gld_lds16(Ag + k0, As + tid * 8);
        gld_lds16(Ag + r64 + k0, As + 2048 + tid * 8);
        gld_lds16(Bg + k0, Bs + tid * 8);
        gld_lds16(Bg + r64 + k0, Bs + 2048 + tid * 8);
        __syncthreads();

        bf16x8 a[4], b[4];
#pragma unroll
        for (int mf = 0; mf < 4; mf++)
            a[mf] = *(const bf16x8*)(As + (mh * 64 + mf * 16 + ln) * 32 + g * 8);
#pragma unroll
        for (int nf = 0; nf < 4; nf++)
            b[nf] = *(const bf16x8*)(Bs + (nh * 64 + nf * 16 + ln) * 32 + g * 8);
#pragma unroll
        for (int mf = 0; mf < 4; mf++)
#pragma unroll
            for (int nf = 0; nf < 4; nf++)
                acc[mf][nf] = mfma16(a[mf], b[nf], acc[mf][nf]);
        __syncthreads();
    }

    if (MODE == 2) {
#pragma unroll
        for (int mf = 0; mf < 4; mf++)
#pragma unroll
            for (int nf = 0; nf < 4; nf++)
#pragma unroll
                for (int r = 0; r < 4; r++) {
                    int row = m_base + mh * 64 + mf * 16 + g * 4 + r;
                    int col = n_base + nh * 64 + nf * 16 + ln;
                    ((float*)C0)[(long)row * N + col] = acc[mf][nf][r];
                }
    } else {
        const int mat = n_base >> 10;   // 0=Q, 1=K, 2=V (uniform per block)
        if (mat < 2) {
            short* dst = (short*)(mat == 0 ? C0 : C1);
#pragma unroll
            for (int mf = 0; mf < 4; mf++)
#pragma unroll
                for (int nf = 0; nf < 4; nf++)
#pragma unroll
                    for (int r = 0; r < 4; r++) {
                        int row = m_base + mh * 64 + mf * 16 + g * 4 + r;
                        int cc = (n_base & 1023) + nh * 64 + nf * 16 + ln;
                        int b_ = row >> 11, t = row & 2047;
                        int h = cc >> 6, d = cc & 63;
                        dst[(((long)(b_ * NHEAD + h) * T_SEQ + t) << 6) + d] =
                            f2bf(acc[mf][nf][r]);
                    }
        } else {
            short* dst = (short*)C2;   // (B,H,dh,T): pack 4 bf16 along t
#pragma unroll
            for (int mf = 0; mf < 4; mf++)
#pragma unroll
                for (int nf = 0; nf < 4; nf++) {
                    short4v pk = { f2bf(acc[mf][nf][0]), f2bf(acc[mf][nf][1]),
                                   f2bf(acc[mf][nf][2]), f2bf(acc[mf][nf][3]) };
                    int cc = (n_base & 1023) + nh * 64 + nf * 16 + ln;
                    int row0 = m_base + mh * 64 + mf * 16 + g * 4;
                    int b_ = row0 >> 11, t = row0 & 2047;
                    *(short4v*)(&dst[((long)(b_ * 1024 + cc) << 11) + t]) = pk;
                }
        }
    }
}

// ---------------------------------------------------------------------------
// Flash attention (causal), unnormalized softmax, LDS-staged K/V.
// Grid 1D 512: id = qxi*32 + bh  (XCD = bh%8 -> per-XCD L2 K/V pinning;
// qx = 15-qxi -> LPT). Block 512 thr = 8 waves x 16 q-rows (128 rows).
// K tile staged as [chunk c][64 keys][32 dh]; V as [c][64 dh][32 keys];
// double-buffered; one barrier per tile.
// ---------------------------------------------------------------------------
__global__ __launch_bounds__(512, 4) void flash_attn(const short* __restrict__ Q,
                                                     const short* __restrict__ Kx,
                                                     const short* __restrict__ Vt,
                                                     short* __restrict__ O) {
    __shared__ short Ks[2][4096];
    __shared__ short Vs[2][4096];
    __shared__ short ldsP[8][16][72];

    const int tid = threadIdx.x;
    const int wv = tid >> 6, lane = tid & 63;
    const int g = lane >> 4, ln = lane & 15;
    const int id = blockIdx.x;
    const int qx = 15 - (id >> 5);
    const int bh = id & 31;

    const short* Kp = Kx + (long)bh * (T_SEQ * DHEAD);
    const short* Vp = Vt + (long)bh * (DHEAD * T_SEQ);

    // staging decomposition: thread t -> chunk, row-in-tile, inner 8 shorts
    const int sch = tid >> 8;
    const int sr = (tid >> 2) & 63;
    const int si = (tid & 3) * 8;
    const int offK = sr * 64 + sch * 32 + si;           // K tile i at +i*4096
    const long offV = (long)sr * T_SEQ + sch * 32 + si; // V tile i at +i*64
    const int ldst = tid * 8;

    const float sc = 0.125f * 1.44269504089f;  // 1/sqrt(dh) * log2(e)
    const int nt = 2 * qx + 2;
    const int qrow0 = qx * 128 + wv * 16;
    const int rl = wv * 16 + g * 4;

    const short* Qp = Q + ((long)bh * T_SEQ + qrow0) * DHEAD;
    bf16x8 qf0 = *(const bf16x8*)(Qp + ln * 64 + 8 * g);
    bf16x8 qf1 = *(const bf16x8*)(Qp + ln * 64 + 32 + 8 * g);

    f32x4 o[4];
#pragma unroll
    for (int nf = 0; nf < 4; nf++) o[nf] = (f32x4){0.f, 0.f, 0.f, 0.f};
    float li[4] = {0.f, 0.f, 0.f, 0.f};

    // pre-stage tile 0 into buffer 0
    gld_lds16(Kp + offK, &Ks[0][ldst]);
    gld_lds16(Vp + offV, &Vs[0][ldst]);

    int buf = 0;
    for (int i = 0; i < nt; i++) {
        __syncthreads();   // staged data for buf visible (vmcnt+lgkm drained)
        if (i + 1 < nt) {
            gld_lds16(Kp + (i + 1) * 4096 + offK, &Ks[buf ^ 1][ldst]);
            gld_lds16(Vp + offV + (i + 1) * 64, &Vs[buf ^ 1][ldst]);
        }

        f32x4 s[4];
#pragma unroll
        for (int j = 0; j < 4; j++) {
            bf16x8 k0 = *(const bf16x8*)(&Ks[buf][(j * 16 + ln) * 32 + 8 * g]);
            bf16x8 k1 = *(const bf16x8*)(&Ks[buf][2048 + (j * 16 + ln) * 32 + 8 * g]);
            s[j] = mfma16(qf0, k0, (f32x4){0.f, 0.f, 0.f, 0.f});
            s[j] = mfma16(qf1, k1, s[j]);
        }

        if (i >= 2 * qx) {   // only last two tiles can cross the diagonal
            const int off = (i - 2 * qx) * 64;
#pragma unroll
            for (int j = 0; j < 4; j++) {
                int kl = off + 16 * j + ln;
#pragma unroll
                for (int r = 0; r < 4; r++)
                    if (kl > rl + r) s[j][r] = -INFINITY;
            }
        }

#pragma unroll
        for (int r = 0; r < 4; r++) {
            float e0 = __builtin_amdgcn_exp2f(s[0][r] * sc);
            float e1 = __builtin_amdgcn_exp2f(s[1][r] * sc);
            float e2 = __builtin_amdgcn_exp2f(s[2][r] * sc);
            float e3 = __builtin_amdgcn_exp2f(s[3][r] * sc);
            li[r] += (e0 + e1) + (e2 + e3);
            ldsP[wv][g * 4 + r][ln] = f2bf(e0);
            ldsP[wv][g * 4 + r][16 + ln] = f2bf(e1);
            ldsP[wv][g * 4 + r][32 + ln] = f2bf(e2);
            ldsP[wv][g * 4 + r][48 + ln] = f2bf(e3);
        }

        asm volatile("s_waitcnt lgkmcnt(0)" ::: "memory");
        bf16x8 pa0 = *(const bf16x8*)(&ldsP[wv][ln][8 * g]);
        bf16x8 pa1 = *(const bf16x8*)(&ldsP[wv][ln][32 + 8 * g]);

#pragma unroll
        for (int nf = 0; nf < 4; nf++) {
            bf16x8 v0 = *(const bf16x8*)(&Vs[buf][(nf * 16 + ln) * 32 + 8 * g]);
            bf16x8 v1 = *(const bf16x8*)(&Vs[buf][2048 + (nf * 16 + ln) * 32 + 8 * g]);
            o[nf] = mfma16(pa0, v0, o[nf]);
            o[nf] = mfma16(pa1, v1, o[nf]);
        }
        buf ^= 1;
    }

#pragma unroll
    for (int r = 0; r < 4; r++) {
        float l = li[r];
        l += __shfl_xor(l, 1);
        l += __shfl_xor(l, 2);
        l += __shfl_xor(l, 4);
        l += __shfl_xor(l, 8);
        li[r] = l;
    }
    const int b = bh >> 4, h = bh & 15;
#pragma unroll
    for (int nf = 0; nf < 4; nf++) {
#pragma unroll
        for (int r = 0; r < 4; r++) {
            int rr = qrow0 + g * 4 + r;
            float v = o[nf][r] / (li[r] + 1e-9f);
            O[((long)(b * T_SEQ + rr) << 10) + h * 64 + nf * 16 + ln] = f2bf(v);
        }
    }
}

// ---------------------------------------------------------------------------
extern "C" void kernel_launch(void* const* d_in, const int* in_sizes, int n_in,
                              void* d_out, int out_size, void* d_ws, size_t ws_size,
                              hipStream_t stream) {
    const float* x  = (const float*)d_in[0];
    const float* Wq = (const float*)d_in[1];
    const float* Wk = (const float*)d_in[2];
    const float* Wv = (const float*)d_in[3];
    const float* Wo = (const float*)d_in[4];

    char* ws = (char*)d_ws;
    short* xb  = (short*)(ws + (0ull  << 20));
    short* wqb = (short*)(ws + (8ull  << 20));   // wq,wk,wv,wo contiguous 2MB each
    short* wob = (short*)(ws + (14ull << 20));
    short* Qb  = (short*)(ws + (16ull << 20));   // (B,H,T,64)
    short* Kb  = (short*)(ws + (24ull << 20));   // (B,H,T,64)
    short* Vtb = (short*)(ws + (32ull << 20));   // (B,H,64,T)
    short* Ab  = (short*)(ws + (40ull << 20));   // (B,T,1024)

    cast_kernel<<<4096, 256, 0, stream>>>(x, xb, 2 * T_SEQ * D_MODEL);
    cast4_kernel<<<dim3(1024, 4), 256, 0, stream>>>(Wq, Wk, Wv, Wo, wqb);

    // fused Q/K/V projection: C = x @ [Wq;Wk;Wv]^T, N = 3072
    gemm128<3><<<dim3(32, 24), 256, 0, stream>>>(xb, wqb, Qb, Kb, Vtb,
                                                 4096, 3072, 1024);

    flash_attn<<<512, 512, 0, stream>>>(Qb, Kb, Vtb, Ab);

    gemm128<2><<<dim3(32, 8), 256, 0, stream>>>(Ab, wob, d_out, nullptr, nullptr,
                                                4096, 1024, 1024);
}

// Round 6
// 175.330 us; speedup vs baseline: 2.8376x; 1.0478x over previous
//
#include <hip/hip_runtime.h>

// ---------------------------------------------------------------------------
// FlashAttentionV2 on MI355X. bf16 MFMA (16x16x32) throughout.
// R4/R5: XOR-swizzled LDS staging everywhere (kills 8-way ds_read_b128 bank
// conflicts; logical chunk c of row r stored at slot c^((r>>1)&3), free via
// global_load_lds address choice). flash_attn: 4-wave/64-row blocks, grid
// 1024 for 3-resident/CU concurrency. Out-proj GEMM 128x64 -> 512 blocks.
// R5 fix: cast d_out to float* at gemm_out call site.
// ---------------------------------------------------------------------------

typedef __attribute__((ext_vector_type(8))) short bf16x8;
typedef __attribute__((ext_vector_type(4))) short short4v;
typedef __attribute__((ext_vector_type(4))) float f32x4;

#define T_SEQ 2048
#define D_MODEL 1024
#define NHEAD 16
#define DHEAD 64

__device__ inline short f2bf(float f) {
    unsigned u = __float_as_uint(f);
    u += 0x7fffu + ((u >> 16) & 1u);   // RNE
    return (short)(u >> 16);
}

__device__ inline f32x4 mfma16(bf16x8 a, bf16x8 b, f32x4 c) {
    return __builtin_amdgcn_mfma_f32_16x16x32_bf16(a, b, c, 0, 0, 0);
}

__device__ inline void gld_lds16(const short* g, short* l) {
    __builtin_amdgcn_global_load_lds(
        (const __attribute__((address_space(1))) void*)g,
        (__attribute__((address_space(3))) void*)l, 16, 0, 0);
}

// ---------------------------------------------------------------------------
__global__ __launch_bounds__(256) void cast_kernel(const float* __restrict__ s,
                                                   short* __restrict__ d, int n) {
    int i = (blockIdx.x * 256 + threadIdx.x) * 4;
    if (i >= n) return;
    float4 v = *(const float4*)(s + i);
    short4v o = { f2bf(v.x), f2bf(v.y), f2bf(v.z), f2bf(v.w) };
    *(short4v*)(d + i) = o;
}

__global__ __launch_bounds__(256) void cast4_kernel(const float* __restrict__ s0,
                                                    const float* __restrict__ s1,
                                                    const float* __restrict__ s2,
                                                    const float* __restrict__ s3,
                                                    short* __restrict__ d) {
    const float* s = (blockIdx.y == 0) ? s0 : (blockIdx.y == 1) ? s1
                   : (blockIdx.y == 2) ? s2 : s3;
    int i = (blockIdx.x * 256 + threadIdx.x) * 4;
    float4 v = *(const float4*)(s + i);
    short4v o = { f2bf(v.x), f2bf(v.y), f2bf(v.z), f2bf(v.w) };
    *(short4v*)(d + blockIdx.y * 1048576 + i) = o;
}

// ---------------------------------------------------------------------------
// Fused QKV GEMM: C = A[M,K] * B[N,K]^T, 128x128 tile, BK=32, swizzled LDS.
// n-block selects Q / K / V^T epilogue scatter (bf16).
// ---------------------------------------------------------------------------
__global__ __launch_bounds__(256, 2) void gemm_qkv(const short* __restrict__ A,
                                                   const short* __restrict__ B,
                                                   short* __restrict__ C0,
                                                   short* __restrict__ C1,
                                                   short* __restrict__ C2,
                                                   int M, int N, int K) {
    __shared__ short As[4096];
    __shared__ short Bs[4096];

    const int tid = threadIdx.x;
    const int wave = tid >> 6, lane = tid & 63;
    const int g = lane >> 4, ln = lane & 15;
    const int mh = wave & 1, nh = wave >> 1;
    const int m_base = blockIdx.x * 128;
    const int n_base = blockIdx.y * 128;
    const int swz8 = 8 * (g ^ ((ln >> 1) & 3));   // reader chunk swizzle

    // staging: thread tid -> row tid>>2, slot tid&3 holds logical chunk
    // c = (tid&3) ^ ((tid>>3)&3); global col offset = c*8
    const int srow = tid >> 2;
    const int scol = (((tid & 3) ^ ((tid >> 3) & 3))) * 8;
    const short* Ag = A + (long)(m_base + srow) * K + scol;
    const short* Bg = B + (long)(n_base + srow) * K + scol;
    const long r64 = 64 * (long)K;

    f32x4 acc[4][4];
#pragma unroll
    for (int i = 0; i < 4; i++)
#pragma unroll
        for (int j = 0; j < 4; j++) acc[i][j] = (f32x4){0.f, 0.f, 0.f, 0.f};

    for (int k0 = 0; k0 < K; k0 += 32) {
        gld_lds16(Ag + k0, As + tid * 8);
        gld_lds16(Ag + r64 + k0, As + 2048 + tid * 8);
        gld_lds16(Bg + k0, Bs + tid * 8);
        gld_lds16(Bg + r64 + k0, Bs + 2048 + tid * 8);
        __syncthreads();

        bf16x8 a[4], b[4];
#pragma unroll
        for (int mf = 0; mf < 4; mf++)
            a[mf] = *(const bf16x8*)(As + (mh * 64 + mf * 16 + ln) * 32 + swz8);
#pragma unroll
        for (int nf = 0; nf < 4; nf++)
            b[nf] = *(const bf16x8*)(Bs + (nh * 64 + nf * 16 + ln) * 32 + swz8);
#pragma unroll
        for (int mf = 0; mf < 4; mf++)
#pragma unroll
            for (int nf = 0; nf < 4; nf++)
                acc[mf][nf] = mfma16(a[mf], b[nf], acc[mf][nf]);
        __syncthreads();
    }

    const int mat = n_base >> 10;   // 0=Q, 1=K, 2=V (uniform per block)
    if (mat < 2) {
        short* dst = mat == 0 ? C0 : C1;
#pragma unroll
        for (int mf = 0; mf < 4; mf++)
#pragma unroll
            for (int nf = 0; nf < 4; nf++)
#pragma unroll
                for (int r = 0; r < 4; r++) {
                    int row = m_base + mh * 64 + mf * 16 + g * 4 + r;
                    int cc = (n_base & 1023) + nh * 64 + nf * 16 + ln;
                    int b_ = row >> 11, t = row & 2047;
                    int h = cc >> 6, d = cc & 63;
                    dst[(((long)(b_ * NHEAD + h) * T_SEQ + t) << 6) + d] =
                        f2bf(acc[mf][nf][r]);
                }
    } else {
        short* dst = C2;   // (B,H,dh,T): pack 4 bf16 along t
#pragma unroll
        for (int mf = 0; mf < 4; mf++)
#pragma unroll
            for (int nf = 0; nf < 4; nf++) {
                short4v pk = { f2bf(acc[mf][nf][0]), f2bf(acc[mf][nf][1]),
                               f2bf(acc[mf][nf][2]), f2bf(acc[mf][nf][3]) };
                int cc = (n_base & 1023) + nh * 64 + nf * 16 + ln;
                int row0 = m_base + mh * 64 + mf * 16 + g * 4;
                int b_ = row0 >> 11, t = row0 & 2047;
                *(short4v*)(&dst[((long)(b_ * 1024 + cc) << 11) + t]) = pk;
            }
    }
}

// ---------------------------------------------------------------------------
// Out-projection GEMM: fp32 C = A[M,K] * B[N,K]^T, 128x64 tile, swizzled LDS.
// 4 waves 2x2, wave tile 64x32. Grid 512 blocks -> 2/CU.
// ---------------------------------------------------------------------------
__global__ __launch_bounds__(256, 2) void gemm_out(const short* __restrict__ A,
                                                   const short* __restrict__ B,
                                                   float* __restrict__ C,
                                                   int M, int N, int K) {
    __shared__ short As[4096];
    __shared__ short Bs[2048];

    const int tid = threadIdx.x;
    const int wave = tid >> 6, lane = tid & 63;
    const int g = lane >> 4, ln = lane & 15;
    const int mh = wave & 1, nh = wave >> 1;
    const int m_base = blockIdx.x * 128;
    const int n_base = blockIdx.y * 64;
    const int swz8 = 8 * (g ^ ((ln >> 1) & 3));

    const int srow = tid >> 2;
    const int scol = (((tid & 3) ^ ((tid >> 3) & 3))) * 8;
    const short* Ag = A + (long)(m_base + srow) * K + scol;
    const short* Bg = B + (long)(n_base + srow) * K + scol;
    const long r64 = 64 * (long)K;

    f32x4 acc[4][2];
#pragma unroll
    for (int i = 0; i < 4; i++)
#pragma unroll
        for (int j = 0; j < 2; j++) acc[i][j] = (f32x4){0.f, 0.f, 0.f, 0.f};

    for (int k0 = 0; k0 < K; k0 += 32) {
        gld_lds16(Ag + k0, As + tid * 8);
        gld_lds16(Ag + r64 + k0, As + 2048 + tid * 8);
        gld_lds16(Bg + k0, Bs + tid * 8);
        __syncthreads();

        bf16x8 a[4], b[2];
#pragma unroll
        for (int mf = 0; mf < 4; mf++)
            a[mf] = *(const bf16x8*)(As + (mh * 64 + mf * 16 + ln) * 32 + swz8);
#pragma unroll
        for (int nf = 0; nf < 2; nf++)
            b[nf] = *(const bf16x8*)(Bs + (nh * 32 + nf * 16 + ln) * 32 + swz8);
#pragma unroll
        for (int mf = 0; mf < 4; mf++)
#pragma unroll
            for (int nf = 0; nf < 2; nf++)
                acc[mf][nf] = mfma16(a[mf], b[nf], acc[mf][nf]);
        __syncthreads();
    }

#pragma unroll
    for (int mf = 0; mf < 4; mf++)
#pragma unroll
        for (int nf = 0; nf < 2; nf++)
#pragma unroll
            for (int r = 0; r < 4; r++) {
                int row = m_base + mh * 64 + mf * 16 + g * 4 + r;
                int col = n_base + nh * 32 + nf * 16 + ln;
                C[(long)row * N + col] = acc[mf][nf][r];
            }
}

// ---------------------------------------------------------------------------
// Flash attention (causal), unnormalized softmax, swizzled LDS-staged K/V.
// Grid 1024: id -> qx = 31-(id>>5) (LPT), bh = id&31 (XCD pin = bh%8).
// Block 256 thr = 4 waves x 16 q-rows (64 rows). 64-key tiles, double-buf.
// ---------------------------------------------------------------------------
__global__ __launch_bounds__(256) void flash_attn(const short* __restrict__ Q,
                                                  const short* __restrict__ Kx,
                                                  const short* __restrict__ Vt,
                                                  short* __restrict__ O) {
    __shared__ short Ks[2][4096];   // [half dh][64 keys][32 shorts], swizzled
    __shared__ short Vs[2][4096];   // [half key][64 dh][32 shorts], swizzled
    __shared__ short ldsP[4][16][72];

    const int tid = threadIdx.x;
    const int wv = tid >> 6, lane = tid & 63;
    const int g = lane >> 4, ln = lane & 15;
    const int id = blockIdx.x;
    const int qx = 31 - (id >> 5);
    const int bh = id & 31;
    const int swz8 = 8 * (g ^ ((ln >> 1) & 3));

    const short* Kp = Kx + (long)bh * (T_SEQ * DHEAD);
    const short* Vp = Vt + (long)bh * (DHEAD * T_SEQ);

    // staging maps: thread tid -> row tid>>2, slot tid&3 holds logical chunk
    const int sr = tid >> 2;
    const int sc8 = (((tid & 3) ^ ((tid >> 3) & 3))) * 8;
    const int offK0 = sr * 64 + sc8;            // + tile*4096 (+32 for half 1)
    const long offV0 = (long)sr * T_SEQ + sc8;  // + tile*64   (+32 for half 1)
    const int ldst = tid * 8;

    const float sc = 0.125f * 1.44269504089f;   // 1/sqrt(dh) * log2(e)
    const int nt = qx + 1;
    const int qrow0 = qx * 64 + wv * 16;
    const int rl = wv * 16 + g * 4;

    const short* Qp = Q + ((long)bh * T_SEQ + qrow0) * DHEAD;
    bf16x8 qf0 = *(const bf16x8*)(Qp + ln * 64 + 8 * g);
    bf16x8 qf1 = *(const bf16x8*)(Qp + ln * 64 + 32 + 8 * g);

    f32x4 o[4];
#pragma unroll
    for (int nf = 0; nf < 4; nf++) o[nf] = (f32x4){0.f, 0.f, 0.f, 0.f};
    float li[4] = {0.f, 0.f, 0.f, 0.f};

    // pre-stage tile 0
    gld_lds16(Kp + offK0, &Ks[0][ldst]);
    gld_lds16(Kp + offK0 + 32, &Ks[0][2048 + ldst]);
    gld_lds16(Vp + offV0, &Vs[0][ldst]);
    gld_lds16(Vp + offV0 + 32, &Vs[0][2048 + ldst]);

    int buf = 0;
    for (int i = 0; i < nt; i++) {
        __syncthreads();   // staged buf visible; buf^1 free for restage
        if (i + 1 < nt) {
            const int kO = (i + 1) * 4096 + offK0;
            const long vO = offV0 + (i + 1) * 64;
            gld_lds16(Kp + kO, &Ks[buf ^ 1][ldst]);
            gld_lds16(Kp + kO + 32, &Ks[buf ^ 1][2048 + ldst]);
            gld_lds16(Vp + vO, &Vs[buf ^ 1][ldst]);
            gld_lds16(Vp + vO + 32, &Vs[buf ^ 1][2048 + ldst]);
        }

        f32x4 s[4];
#pragma unroll
        for (int j = 0; j < 4; j++) {
            bf16x8 k0 = *(const bf16x8*)(&Ks[buf][(j * 16 + ln) * 32 + swz8]);
            bf16x8 k1 = *(const bf16x8*)(&Ks[buf][2048 + (j * 16 + ln) * 32 + swz8]);
            s[j] = mfma16(qf0, k0, (f32x4){0.f, 0.f, 0.f, 0.f});
            s[j] = mfma16(qf1, k1, s[j]);
        }

        if (i == nt - 1) {   // diagonal tile
#pragma unroll
            for (int j = 0; j < 4; j++) {
                int kl = 16 * j + ln;
#pragma unroll
                for (int r = 0; r < 4; r++)
                    if (kl > rl + r) s[j][r] = -INFINITY;
            }
        }

#pragma unroll
        for (int r = 0; r < 4; r++) {
            float e0 = __builtin_amdgcn_exp2f(s[0][r] * sc);
            float e1 = __builtin_amdgcn_exp2f(s[1][r] * sc);
            float e2 = __builtin_amdgcn_exp2f(s[2][r] * sc);
            float e3 = __builtin_amdgcn_exp2f(s[3][r] * sc);
            li[r] += (e0 + e1) + (e2 + e3);
            ldsP[wv][g * 4 + r][ln] = f2bf(e0);
            ldsP[wv][g * 4 + r][16 + ln] = f2bf(e1);
            ldsP[wv][g * 4 + r][32 + ln] = f2bf(e2);
            ldsP[wv][g * 4 + r][48 + ln] = f2bf(e3);
        }

        asm volatile("s_waitcnt lgkmcnt(0)" ::: "memory");
        bf16x8 pa0 = *(const bf16x8*)(&ldsP[wv][ln][8 * g]);
        bf16x8 pa1 = *(const bf16x8*)(&ldsP[wv][ln][32 + 8 * g]);

#pragma unroll
        for (int nf = 0; nf < 4; nf++) {
            bf16x8 v0 = *(const bf16x8*)(&Vs[buf][(nf * 16 + ln) * 32 + swz8]);
            bf16x8 v1 = *(const bf16x8*)(&Vs[buf][2048 + (nf * 16 + ln) * 32 + swz8]);
            o[nf] = mfma16(pa0, v0, o[nf]);
            o[nf] = mfma16(pa1, v1, o[nf]);
        }
        buf ^= 1;
    }

#pragma unroll
    for (int r = 0; r < 4; r++) {
        float l = li[r];
        l += __shfl_xor(l, 1);
        l += __shfl_xor(l, 2);
        l += __shfl_xor(l, 4);
        l += __shfl_xor(l, 8);
        li[r] = l;
    }
    const int b = bh >> 4, h = bh & 15;
#pragma unroll
    for (int nf = 0; nf < 4; nf++) {
#pragma unroll
        for (int r = 0; r < 4; r++) {
            int rr = qrow0 + g * 4 + r;
            float v = o[nf][r] / (li[r] + 1e-9f);
            O[((long)(b * T_SEQ + rr) << 10) + h * 64 + nf * 16 + ln] = f2bf(v);
        }
    }
}

// ---------------------------------------------------------------------------
extern "C" void kernel_launch(void* const* d_in, const int* in_sizes, int n_in,
                              void* d_out, int out_size, void* d_ws, size_t ws_size,
                              hipStream_t stream) {
    const float* x  = (const float*)d_in[0];
    const float* Wq = (const float*)d_in[1];
    const float* Wk = (const float*)d_in[2];
    const float* Wv = (const float*)d_in[3];
    const float* Wo = (const float*)d_in[4];

    char* ws = (char*)d_ws;
    short* xb  = (short*)(ws + (0ull  << 20));
    short* wqb = (short*)(ws + (8ull  << 20));   // wq,wk,wv,wo contiguous 2MB each
    short* wob = (short*)(ws + (14ull << 20));
    short* Qb  = (short*)(ws + (16ull << 20));   // (B,H,T,64)
    short* Kb  = (short*)(ws + (24ull << 20));   // (B,H,T,64)
    short* Vtb = (short*)(ws + (32ull << 20));   // (B,H,64,T)
    short* Ab  = (short*)(ws + (40ull << 20));   // (B,T,1024)

    cast_kernel<<<4096, 256, 0, stream>>>(x, xb, 2 * T_SEQ * D_MODEL);
    cast4_kernel<<<dim3(1024, 4), 256, 0, stream>>>(Wq, Wk, Wv, Wo, wqb);

    // fused Q/K/V projection: C = x @ [Wq;Wk;Wv]^T, N = 3072
    gemm_qkv<<<dim3(32, 24), 256, 0, stream>>>(xb, wqb, Qb, Kb, Vtb,
                                               4096, 3072, 1024);

    flash_attn<<<1024, 256, 0, stream>>>(Qb, Kb, Vtb, Ab);

    gemm_out<<<dim3(32, 16), 256, 0, stream>>>(Ab, wob, (float*)d_out,
                                               4096, 1024, 1024);
}

// Round 7
// 169.993 us; speedup vs baseline: 2.9267x; 1.0314x over previous
//
#include <hip/hip_runtime.h>

// ---------------------------------------------------------------------------
// FlashAttentionV2 on MI355X. bf16 MFMA (16x16x32) throughout.
// R6: transposed-scores flash (S^T = K*Q^T via operand swap; P-write becomes
// 4x ds_write_b64, li becomes one scalar/lane), V-reads hoisted, GEMMs at
// launch_bounds(256,3) for 3 blocks/CU.
// ---------------------------------------------------------------------------

typedef __attribute__((ext_vector_type(8))) short bf16x8;
typedef __attribute__((ext_vector_type(4))) short short4v;
typedef __attribute__((ext_vector_type(4))) float f32x4;

#define T_SEQ 2048
#define D_MODEL 1024
#define NHEAD 16
#define DHEAD 64

__device__ inline short f2bf(float f) {
    unsigned u = __float_as_uint(f);
    u += 0x7fffu + ((u >> 16) & 1u);   // RNE
    return (short)(u >> 16);
}

__device__ inline unsigned long long pack4bf(float a, float b, float c, float d) {
    return (unsigned long long)(unsigned short)f2bf(a)
         | ((unsigned long long)(unsigned short)f2bf(b) << 16)
         | ((unsigned long long)(unsigned short)f2bf(c) << 32)
         | ((unsigned long long)(unsigned short)f2bf(d) << 48);
}

__device__ inline f32x4 mfma16(bf16x8 a, bf16x8 b, f32x4 c) {
    return __builtin_amdgcn_mfma_f32_16x16x32_bf16(a, b, c, 0, 0, 0);
}

__device__ inline void gld_lds16(const short* g, short* l) {
    __builtin_amdgcn_global_load_lds(
        (const __attribute__((address_space(1))) void*)g,
        (__attribute__((address_space(3))) void*)l, 16, 0, 0);
}

// ---------------------------------------------------------------------------
__global__ __launch_bounds__(256) void cast_kernel(const float* __restrict__ s,
                                                   short* __restrict__ d, int n) {
    int i = (blockIdx.x * 256 + threadIdx.x) * 4;
    if (i >= n) return;
    float4 v = *(const float4*)(s + i);
    short4v o = { f2bf(v.x), f2bf(v.y), f2bf(v.z), f2bf(v.w) };
    *(short4v*)(d + i) = o;
}

__global__ __launch_bounds__(256) void cast4_kernel(const float* __restrict__ s0,
                                                    const float* __restrict__ s1,
                                                    const float* __restrict__ s2,
                                                    const float* __restrict__ s3,
                                                    short* __restrict__ d) {
    const float* s = (blockIdx.y == 0) ? s0 : (blockIdx.y == 1) ? s1
                   : (blockIdx.y == 2) ? s2 : s3;
    int i = (blockIdx.x * 256 + threadIdx.x) * 4;
    float4 v = *(const float4*)(s + i);
    short4v o = { f2bf(v.x), f2bf(v.y), f2bf(v.z), f2bf(v.w) };
    *(short4v*)(d + blockIdx.y * 1048576 + i) = o;
}

// ---------------------------------------------------------------------------
// Fused QKV GEMM: C = A[M,K] * B[N,K]^T, 128x128 tile, BK=32, swizzled LDS.
// ---------------------------------------------------------------------------
__global__ __launch_bounds__(256, 3) void gemm_qkv(const short* __restrict__ A,
                                                   const short* __restrict__ B,
                                                   short* __restrict__ C0,
                                                   short* __restrict__ C1,
                                                   short* __restrict__ C2,
                                                   int M, int N, int K) {
    __shared__ short As[4096];
    __shared__ short Bs[4096];

    const int tid = threadIdx.x;
    const int wave = tid >> 6, lane = tid & 63;
    const int g = lane >> 4, ln = lane & 15;
    const int mh = wave & 1, nh = wave >> 1;
    const int m_base = blockIdx.x * 128;
    const int n_base = blockIdx.y * 128;
    const int swz8 = 8 * (g ^ ((ln >> 1) & 3));

    const int srow = tid >> 2;
    const int scol = (((tid & 3) ^ ((tid >> 3) & 3))) * 8;
    const short* Ag = A + (long)(m_base + srow) * K + scol;
    const short* Bg = B + (long)(n_base + srow) * K + scol;
    const long r64 = 64 * (long)K;

    f32x4 acc[4][4];
#pragma unroll
    for (int i = 0; i < 4; i++)
#pragma unroll
        for (int j = 0; j < 4; j++) acc[i][j] = (f32x4){0.f, 0.f, 0.f, 0.f};

    for (int k0 = 0; k0 < K; k0 += 32) {
        gld_lds16(Ag + k0, As + tid * 8);
        gld_lds16(Ag + r64 + k0, As + 2048 + tid * 8);
        gld_lds16(Bg + k0, Bs + tid * 8);
        gld_lds16(Bg + r64 + k0, Bs + 2048 + tid * 8);
        __syncthreads();

        bf16x8 a[4], b[4];
#pragma unroll
        for (int mf = 0; mf < 4; mf++)
            a[mf] = *(const bf16x8*)(As + (mh * 64 + mf * 16 + ln) * 32 + swz8);
#pragma unroll
        for (int nf = 0; nf < 4; nf++)
            b[nf] = *(const bf16x8*)(Bs + (nh * 64 + nf * 16 + ln) * 32 + swz8);
#pragma unroll
        for (int mf = 0; mf < 4; mf++)
#pragma unroll
            for (int nf = 0; nf < 4; nf++)
                acc[mf][nf] = mfma16(a[mf], b[nf], acc[mf][nf]);
        __syncthreads();
    }

    const int mat = n_base >> 10;   // 0=Q, 1=K, 2=V (uniform per block)
    if (mat < 2) {
        short* dst = mat == 0 ? C0 : C1;
#pragma unroll
        for (int mf = 0; mf < 4; mf++)
#pragma unroll
            for (int nf = 0; nf < 4; nf++)
#pragma unroll
                for (int r = 0; r < 4; r++) {
                    int row = m_base + mh * 64 + mf * 16 + g * 4 + r;
                    int cc = (n_base & 1023) + nh * 64 + nf * 16 + ln;
                    int b_ = row >> 11, t = row & 2047;
                    int h = cc >> 6, d = cc & 63;
                    dst[(((long)(b_ * NHEAD + h) * T_SEQ + t) << 6) + d] =
                        f2bf(acc[mf][nf][r]);
                }
    } else {
        short* dst = C2;   // (B,H,dh,T): pack 4 bf16 along t
#pragma unroll
        for (int mf = 0; mf < 4; mf++)
#pragma unroll
            for (int nf = 0; nf < 4; nf++) {
                short4v pk = { f2bf(acc[mf][nf][0]), f2bf(acc[mf][nf][1]),
                               f2bf(acc[mf][nf][2]), f2bf(acc[mf][nf][3]) };
                int cc = (n_base & 1023) + nh * 64 + nf * 16 + ln;
                int row0 = m_base + mh * 64 + mf * 16 + g * 4;
                int b_ = row0 >> 11, t = row0 & 2047;
                *(short4v*)(&dst[((long)(b_ * 1024 + cc) << 11) + t]) = pk;
            }
    }
}

// ---------------------------------------------------------------------------
// Out-projection GEMM: fp32 C = A[M,K] * B[N,K]^T, 128x64 tile, swizzled LDS.
// ---------------------------------------------------------------------------
__global__ __launch_bounds__(256, 3) void gemm_out(const short* __restrict__ A,
                                                   const short* __restrict__ B,
                                                   float* __restrict__ C,
                                                   int M, int N, int K) {
    __shared__ short As[4096];
    __shared__ short Bs[2048];

    const int tid = threadIdx.x;
    const int wave = tid >> 6, lane = tid & 63;
    const int g = lane >> 4, ln = lane & 15;
    const int mh = wave & 1, nh = wave >> 1;
    const int m_base = blockIdx.x * 128;
    const int n_base = blockIdx.y * 64;
    const int swz8 = 8 * (g ^ ((ln >> 1) & 3));

    const int srow = tid >> 2;
    const int scol = (((tid & 3) ^ ((tid >> 3) & 3))) * 8;
    const short* Ag = A + (long)(m_base + srow) * K + scol;
    const short* Bg = B + (long)(n_base + srow) * K + scol;
    const long r64 = 64 * (long)K;

    f32x4 acc[4][2];
#pragma unroll
    for (int i = 0; i < 4; i++)
#pragma unroll
        for (int j = 0; j < 2; j++) acc[i][j] = (f32x4){0.f, 0.f, 0.f, 0.f};

    for (int k0 = 0; k0 < K; k0 += 32) {
        gld_lds16(Ag + k0, As + tid * 8);
        gld_lds16(Ag + r64 + k0, As + 2048 + tid * 8);
        gld_lds16(Bg + k0, Bs + tid * 8);
        __syncthreads();

        bf16x8 a[4], b[2];
#pragma unroll
        for (int mf = 0; mf < 4; mf++)
            a[mf] = *(const bf16x8*)(As + (mh * 64 + mf * 16 + ln) * 32 + swz8);
#pragma unroll
        for (int nf = 0; nf < 2; nf++)
            b[nf] = *(const bf16x8*)(Bs + (nh * 32 + nf * 16 + ln) * 32 + swz8);
#pragma unroll
        for (int mf = 0; mf < 4; mf++)
#pragma unroll
            for (int nf = 0; nf < 2; nf++)
                acc[mf][nf] = mfma16(a[mf], b[nf], acc[mf][nf]);
        __syncthreads();
    }

#pragma unroll
    for (int mf = 0; mf < 4; mf++)
#pragma unroll
        for (int nf = 0; nf < 2; nf++)
#pragma unroll
            for (int r = 0; r < 4; r++) {
                int row = m_base + mh * 64 + mf * 16 + g * 4 + r;
                int col = n_base + nh * 32 + nf * 16 + ln;
                C[(long)row * N + col] = acc[mf][nf][r];
            }
}

// ---------------------------------------------------------------------------
// Flash attention (causal), unnormalized softmax, transposed scores.
// S^T = K*Q^T (operand-swapped MFMA): lane(g,ln) holds s[j][r] =
// S[q=ln][key=16j+4g+r] -> P row q=ln gets 4 consecutive keys per (j):
// one ds_write_b64 each. li = single scalar/lane (q=ln), reduced at end.
// Grid 1024: qx = 31-(id>>5) (LPT), bh = id&31 (XCD pin). 4 waves x 16 rows.
// ---------------------------------------------------------------------------
__global__ __launch_bounds__(256) void flash_attn(const short* __restrict__ Q,
                                                  const short* __restrict__ Kx,
                                                  const short* __restrict__ Vt,
                                                  short* __restrict__ O) {
    __shared__ short Ks[2][4096];    // [half dh][64 keys][32 shorts], swizzled
    __shared__ short Vs[2][4096];    // [half key][64 dh][32 shorts], swizzled
    __shared__ short ldsP[4][16][68];  // [wave][q][64 keys], stride 68

    const int tid = threadIdx.x;
    const int wv = tid >> 6, lane = tid & 63;
    const int g = lane >> 4, ln = lane & 15;
    const int id = blockIdx.x;
    const int qx = 31 - (id >> 5);
    const int bh = id & 31;
    const int swz8 = 8 * (g ^ ((ln >> 1) & 3));

    const short* Kp = Kx + (long)bh * (T_SEQ * DHEAD);
    const short* Vp = Vt + (long)bh * (DHEAD * T_SEQ);

    const int sr = tid >> 2;
    const int sc8 = (((tid & 3) ^ ((tid >> 3) & 3))) * 8;
    const int offK0 = sr * 64 + sc8;
    const long offV0 = (long)sr * T_SEQ + sc8;
    const int ldst = tid * 8;

    const float sc = 0.125f * 1.44269504089f;   // 1/sqrt(dh) * log2(e)
    const int nt = qx + 1;
    const int qrow0 = qx * 64 + wv * 16;

    const short* Qp = Q + ((long)bh * T_SEQ + qrow0) * DHEAD;
    bf16x8 qf0 = *(const bf16x8*)(Qp + ln * 64 + 8 * g);
    bf16x8 qf1 = *(const bf16x8*)(Qp + ln * 64 + 32 + 8 * g);

    f32x4 o[4];
#pragma unroll
    for (int nf = 0; nf < 4; nf++) o[nf] = (f32x4){0.f, 0.f, 0.f, 0.f};
    float li = 0.f;   // unnormalized denom for q = ln (partial over this lane's keys)

    // pre-stage tile 0
    gld_lds16(Kp + offK0, &Ks[0][ldst]);
    gld_lds16(Kp + offK0 + 32, &Ks[0][2048 + ldst]);
    gld_lds16(Vp + offV0, &Vs[0][ldst]);
    gld_lds16(Vp + offV0 + 32, &Vs[0][2048 + ldst]);

    int buf = 0;
    for (int i = 0; i < nt; i++) {
        __syncthreads();
        if (i + 1 < nt) {
            const int kO = (i + 1) * 4096 + offK0;
            const long vO = offV0 + (i + 1) * 64;
            gld_lds16(Kp + kO, &Ks[buf ^ 1][ldst]);
            gld_lds16(Kp + kO + 32, &Ks[buf ^ 1][2048 + ldst]);
            gld_lds16(Vp + vO, &Vs[buf ^ 1][ldst]);
            gld_lds16(Vp + vO + 32, &Vs[buf ^ 1][2048 + ldst]);
        }

        // S^T: A = K-frag (key = m), B = Q-frag (q = n)
        f32x4 s[4];
#pragma unroll
        for (int j = 0; j < 4; j++) {
            bf16x8 k0 = *(const bf16x8*)(&Ks[buf][(j * 16 + ln) * 32 + swz8]);
            bf16x8 k1 = *(const bf16x8*)(&Ks[buf][2048 + (j * 16 + ln) * 32 + swz8]);
            s[j] = mfma16(k0, qf0, (f32x4){0.f, 0.f, 0.f, 0.f});
            s[j] = mfma16(k1, qf1, s[j]);
        }

        // V loads hoisted (independent of softmax)
        bf16x8 vf[4][2];
#pragma unroll
        for (int nf = 0; nf < 4; nf++) {
            vf[nf][0] = *(const bf16x8*)(&Vs[buf][(nf * 16 + ln) * 32 + swz8]);
            vf[nf][1] = *(const bf16x8*)(&Vs[buf][2048 + (nf * 16 + ln) * 32 + swz8]);
        }

        if (i == nt - 1) {   // diagonal: mask key_local(16j+4g+r) > q_local(16wv+ln)
            const int ql = 16 * wv + ln;
#pragma unroll
            for (int j = 0; j < 4; j++) {
                int kl = 16 * j + 4 * g;
#pragma unroll
                for (int r = 0; r < 4; r++)
                    if (kl + r > ql) s[j][r] = -INFINITY;
            }
        }

#pragma unroll
        for (int j = 0; j < 4; j++) {
            float e0 = __builtin_amdgcn_exp2f(s[j][0] * sc);
            float e1 = __builtin_amdgcn_exp2f(s[j][1] * sc);
            float e2 = __builtin_amdgcn_exp2f(s[j][2] * sc);
            float e3 = __builtin_amdgcn_exp2f(s[j][3] * sc);
            li += (e0 + e1) + (e2 + e3);
            *(unsigned long long*)(&ldsP[wv][ln][16 * j + 4 * g]) =
                pack4bf(e0, e1, e2, e3);
        }

        asm volatile("s_waitcnt lgkmcnt(0)" ::: "memory");
        bf16x8 pa0 = *(const bf16x8*)(&ldsP[wv][ln][8 * g]);
        bf16x8 pa1 = *(const bf16x8*)(&ldsP[wv][ln][32 + 8 * g]);

#pragma unroll
        for (int nf = 0; nf < 4; nf++) {
            o[nf] = mfma16(pa0, vf[nf][0], o[nf]);
            o[nf] = mfma16(pa1, vf[nf][1], o[nf]);
        }
        buf ^= 1;
    }

    // li: partial sums over quads -> full denom for q=ln on every lane
    li += __shfl_xor(li, 16);
    li += __shfl_xor(li, 32);

    float lr[4];
#pragma unroll
    for (int r = 0; r < 4; r++)
        lr[r] = 1.f / (__shfl(li, 4 * g + r) + 1e-9f);

    const int b = bh >> 4, h = bh & 15;
#pragma unroll
    for (int nf = 0; nf < 4; nf++) {
#pragma unroll
        for (int r = 0; r < 4; r++) {
            int rr = qrow0 + g * 4 + r;
            O[((long)(b * T_SEQ + rr) << 10) + h * 64 + nf * 16 + ln] =
                f2bf(o[nf][r] * lr[r]);
        }
    }
}

// ---------------------------------------------------------------------------
extern "C" void kernel_launch(void* const* d_in, const int* in_sizes, int n_in,
                              void* d_out, int out_size, void* d_ws, size_t ws_size,
                              hipStream_t stream) {
    const float* x  = (const float*)d_in[0];
    const float* Wq = (const float*)d_in[1];
    const float* Wk = (const float*)d_in[2];
    const float* Wv = (const float*)d_in[3];
    const float* Wo = (const float*)d_in[4];

    char* ws = (char*)d_ws;
    short* xb  = (short*)(ws + (0ull  << 20));
    short* wqb = (short*)(ws + (8ull  << 20));   // wq,wk,wv,wo contiguous 2MB each
    short* wob = (short*)(ws + (14ull << 20));
    short* Qb  = (short*)(ws + (16ull << 20));   // (B,H,T,64)
    short* Kb  = (short*)(ws + (24ull << 20));   // (B,H,T,64)
    short* Vtb = (short*)(ws + (32ull << 20));   // (B,H,64,T)
    short* Ab  = (short*)(ws + (40ull << 20));   // (B,T,1024)

    cast_kernel<<<4096, 256, 0, stream>>>(x, xb, 2 * T_SEQ * D_MODEL);
    cast4_kernel<<<dim3(1024, 4), 256, 0, stream>>>(Wq, Wk, Wv, Wo, wqb);

    gemm_qkv<<<dim3(32, 24), 256, 0, stream>>>(xb, wqb, Qb, Kb, Vtb,
                                               4096, 3072, 1024);

    flash_attn<<<1024, 256, 0, stream>>>(Qb, Kb, Vtb, Ab);

    gemm_out<<<dim3(32, 16), 256, 0, stream>>>(Ab, wob, (float*)d_out,
                                               4096, 1024, 1024);
}